// Round 11
// baseline (72.326 us; speedup 1.0000x reference)
//
#include <hip/hip_runtime.h>
#include <stdint.h>

typedef _Float16 f16x8 __attribute__((ext_vector_type(8)));
typedef __fp16 fp16x2 __attribute__((ext_vector_type(2)));
typedef float f32x4 __attribute__((ext_vector_type(4)));

#define BC (16384 * 256)

__device__ __forceinline__ f16x8 cvt8(f32x4 a, f32x4 b) {
  fp16x2 p0 = __builtin_amdgcn_cvt_pkrtz(a[0], a[1]);
  fp16x2 p1 = __builtin_amdgcn_cvt_pkrtz(a[2], a[3]);
  fp16x2 p2 = __builtin_amdgcn_cvt_pkrtz(b[0], b[1]);
  fp16x2 p3 = __builtin_amdgcn_cvt_pkrtz(b[2], b[3]);
  f16x8 o;
  o[0] = (_Float16)p0[0]; o[1] = (_Float16)p0[1];
  o[2] = (_Float16)p1[0]; o[3] = (_Float16)p1[1];
  o[4] = (_Float16)p2[0]; o[5] = (_Float16)p2[1];
  o[6] = (_Float16)p3[0]; o[7] = (_Float16)p3[1];
  return o;
}

__device__ __forceinline__ float tanh_fast(float v) {
  float a = fminf(fabsf(v), 18.f);
  float t = __expf(2.f * a);
  float r = (t - 1.f) * __builtin_amdgcn_rcpf(t + 1.f);
  return copysignf(r, v);
}

// Pack Wu/Wg/Wa/Wd -> wsB f16, PRE-SWIZZLED (R6 layout, verified):
// wsB[cb*65536 + row*512 + kt*64 + slot*8 + b] where
//   row = wn*64 + strip*16 + t16, c = cb*32 + wn*16 + t16,
//   k = kt*64 + (slot ^ (row&7))*8 + b  (XOR swizzle baked in).
// strip: 0=Wu (K zero-padded for k>=256), 1=Wg, 2=Wa, 3=Wd.
__global__ __launch_bounds__(256) void pack_w(const float* __restrict__ Wu,
                                              const float* __restrict__ Wg,
                                              const float* __restrict__ Wa,
                                              const float* __restrict__ Wd,
                                              _Float16* __restrict__ wsB) {
  int t = blockIdx.x * 256 + threadIdx.x;  // 65536 total
  int slot = t & 7;
  int kt = (t >> 3) & 7;
  int row = (t >> 6) & 127;
  int cb = t >> 13;
  int strip = (row >> 4) & 3;
  int wn = row >> 6;
  int t16 = row & 15;
  int c = cb * 32 + wn * 16 + t16;
  int k0 = kt * 64 + (slot ^ (row & 7)) * 8;
  float v[8];
  if (strip == 0) {
    if (k0 < 256) {
      const float* p = Wu + (size_t)c * 256 + k0;
#pragma unroll
      for (int i = 0; i < 8; ++i) v[i] = p[i];
    } else {
#pragma unroll
      for (int i = 0; i < 8; ++i) v[i] = 0.f;
    }
  } else {
    const float* p = (strip == 1 ? Wg : (strip == 2 ? Wa : Wd)) + (size_t)c * 512 + k0;
#pragma unroll
    for (int i = 0; i < 8; ++i) v[i] = p[i];
  }
  f32x4 a = {v[0], v[1], v[2], v[3]};
  f32x4 b = {v[4], v[5], v[6], v[7]};
  *reinterpret_cast<f16x8*>(wsB + (size_t)cb * 65536 + row * 512 + kt * 64 + slot * 8) =
      cvt8(a, b);
}

// R6 structure (best measured: 52.6 us) + T14 epilogue-load hoist:
// Block: 64 rows x 128 packed cols, 4 waves (2M x 2N), BK=64, 24 KB LDS
// single-buffered -> 6 blocks/CU. All epilogue input loads (amax/n/d x 8,
// bu, bg) are issued BEFORE the k-loop so they fly under the GEMM phase;
// the epilogue is pure compute + stores.
__global__ __launch_bounds__(256, 6) void rwa_main(
    const float* __restrict__ x, const float* __restrict__ nt_,
    const float* __restrict__ dt_, const float* __restrict__ h,
    const float* __restrict__ amax_, const float* __restrict__ bu,
    const float* __restrict__ bg, const _Float16* __restrict__ wsB,
    float* __restrict__ out) {
  __shared__ __align__(16) _Float16 ldsA[64 * 64];   // 8 KB
  __shared__ __align__(16) _Float16 ldsB[128 * 64];  // 16 KB

  const int tid = threadIdx.x;
  const int lane = tid & 63;
  const int l15 = lane & 15;
  const int lg = lane >> 4;
  const int wv = tid >> 6;
  const int wm = wv & 1;   // wave row-half (32 rows)
  const int wn = wv >> 1;  // wave packed-col half (64)

  // XCD swizzle: per XCD, cb fastest -> row panels + weights L2-hot.
  const int bid = blockIdx.x;
  const int xcd = bid & 7;
  const int q = bid >> 3;
  const int cb = q & 7;
  const int rowblk = xcd * 32 + (q >> 3);
  const int row0 = rowblk * 64;

  // A staging: thread stages row ar (0..63), k-quarter aq (16 floats).
  const int ar = tid >> 2;
  const int aq = tid & 3;

  // B staging source (R6 layout).
  const _Float16* bsrc0 = wsB + (size_t)cb * 65536 + (tid >> 3) * 512 + (tid & 7) * 8;

  // ---- T14: hoist ALL epilogue input loads before the k-loop ----
  const int c = cb * 32 + wn * 16 + l15;
  const float buv = bu[c];
  const float bgv = bg[c];
  float am_h[2][4], n_h[2][4], d_h[2][4];
#pragma unroll
  for (int mi = 0; mi < 2; ++mi) {
#pragma unroll
    for (int rg = 0; rg < 4; ++rg) {
      const int r = row0 + wm * 32 + mi * 16 + lg * 4 + rg;
      const int idx = r * 256 + c;
      am_h[mi][rg] = amax_[idx];
      n_h[mi][rg] = nt_[idx];
      d_h[mi][rg] = dt_[idx];
    }
  }
  __builtin_amdgcn_sched_barrier(0);  // keep the hoisted loads up here

  f32x4 acc[2][4] = {};  // [mi][strip]

  for (int kt = 0; kt < 8; ++kt) {
    // --- stage B: 4x global_load_lds dwordx4 (linear dest, pre-swizzled src) ---
#pragma unroll
    for (int i = 0; i < 4; ++i) {
      __builtin_amdgcn_global_load_lds(
          (const __attribute__((address_space(1))) uint32_t*)(bsrc0 + (size_t)kt * 64 + i * 16384),
          (__attribute__((address_space(3))) uint32_t*)(ldsB + wv * 512 + i * 2048),
          16, 0, 0);
    }
    // --- stage A: coalesced f32 loads, cvt f16, swizzled ds_write ---
    {
      const float* asrc =
          (kt < 4 ? x : h) + (size_t)(row0 + ar) * 256 + (kt & 3) * 64 + aq * 16;
      f32x4 av[4];
#pragma unroll
      for (int i = 0; i < 4; ++i) av[i] = *reinterpret_cast<const f32x4*>(asrc + i * 4);
#pragma unroll
      for (int j = 0; j < 2; ++j) {
        f16x8 o = cvt8(av[2 * j], av[2 * j + 1]);
        const int slot = (aq * 2 + j) ^ (ar & 7);
        *reinterpret_cast<f16x8*>(reinterpret_cast<char*>(ldsA) + ar * 128 + slot * 16) = o;
      }
    }
    __syncthreads();

    // --- compute ---
    const bool doU = (kt < 4);  // Wu strip zero-padded beyond k=256
    const int rswz = (l15 & 7) << 4;
#pragma unroll
    for (int ks = 0; ks < 2; ++ks) {
      f16x8 af[2], bf[4];
#pragma unroll
      for (int mi = 0; mi < 2; ++mi) {
        const int row = wm * 32 + mi * 16 + l15;
        af[mi] = *reinterpret_cast<const f16x8*>(
            reinterpret_cast<const char*>(ldsA) + row * 128 + ((ks * 64 + lg * 16) ^ rswz));
      }
#pragma unroll
      for (int s = 0; s < 4; ++s) {
        if (s == 0 && !doU) continue;
        const int pc = wn * 64 + s * 16 + l15;
        bf[s] = *reinterpret_cast<const f16x8*>(
            reinterpret_cast<const char*>(ldsB) + pc * 128 + ((ks * 64 + lg * 16) ^ rswz));
      }
#pragma unroll
      for (int s = 0; s < 4; ++s) {
        if (s == 0 && !doU) continue;
#pragma unroll
        for (int mi = 0; mi < 2; ++mi)
          acc[mi][s] = __builtin_amdgcn_mfma_f32_16x16x32_f16(af[mi], bf[s], acc[mi][s], 0, 0, 0);
      }
    }
    __syncthreads();
  }

  // --- epilogue: pure compute + stores (inputs already in registers) ---
#pragma unroll
  for (int mi = 0; mi < 2; ++mi) {
#pragma unroll
    for (int rg = 0; rg < 4; ++rg) {
      const int r = row0 + wm * 32 + mi * 16 + lg * 4 + rg;
      const int idx = r * 256 + c;
      const float u = acc[mi][0][rg] + buv;
      const float gt = acc[mi][1][rg] + bgv;
      const float a = acc[mi][2][rg];
      const float dr = acc[mi][3][rg];
      const float sig = __builtin_amdgcn_rcpf(1.f + __expf(-dr));
      const float z = u * tanh_fast(gt);
      const float am = am_h[mi][rg];
      const float e_neg = __expf(-sig);
      const float a_new = fmaxf(am * e_neg, a);
      const float comm = __expf(am - a_new - sig);  // e_neg * exp(am - a_new)
      const float escal = __expf(a - a_new);
      const float n_new = n_h[mi][rg] * comm + z * escal;
      const float d_new = d_h[mi][rg] * comm + escal;
      const float h_new = tanh_fast(n_new * __builtin_amdgcn_rcpf(d_new));
      out[idx] = n_new;
      out[BC + idx] = d_new;
      out[2 * BC + idx] = h_new;
      out[3 * BC + idx] = a_new;
    }
  }
}

extern "C" void kernel_launch(void* const* d_in, const int* in_sizes, int n_in,
                              void* d_out, int out_size, void* d_ws, size_t ws_size,
                              hipStream_t stream) {
  const float* x_t    = (const float*)d_in[0];
  const float* n_t    = (const float*)d_in[1];
  const float* d_t    = (const float*)d_in[2];
  const float* h_t    = (const float*)d_in[3];
  const float* amax_t = (const float*)d_in[4];
  const float* Wu     = (const float*)d_in[5];
  const float* bu     = (const float*)d_in[6];
  const float* Wg     = (const float*)d_in[7];
  const float* bg     = (const float*)d_in[8];
  const float* Wa     = (const float*)d_in[9];
  const float* Wd     = (const float*)d_in[10];
  float* out = (float*)d_out;

  _Float16* wsB = (_Float16*)d_ws;  // 1 MB pre-swizzled packed weights

  pack_w<<<256, 256, 0, stream>>>(Wu, Wg, Wa, Wd, wsB);
  rwa_main<<<2048, 256, 0, stream>>>(x_t, n_t, d_t, h_t, amax_t, bu, bg, wsB, out);
}

// Round 12
// 51.950 us; speedup vs baseline: 1.3922x; 1.3922x over previous
//
#include <hip/hip_runtime.h>
#include <stdint.h>

typedef _Float16 f16x8 __attribute__((ext_vector_type(8)));
typedef __fp16 fp16x2 __attribute__((ext_vector_type(2)));
typedef float f32x4 __attribute__((ext_vector_type(4)));

#define BC (16384 * 256)

__device__ __forceinline__ f16x8 cvt8(f32x4 a, f32x4 b) {
  fp16x2 p0 = __builtin_amdgcn_cvt_pkrtz(a[0], a[1]);
  fp16x2 p1 = __builtin_amdgcn_cvt_pkrtz(a[2], a[3]);
  fp16x2 p2 = __builtin_amdgcn_cvt_pkrtz(b[0], b[1]);
  fp16x2 p3 = __builtin_amdgcn_cvt_pkrtz(b[2], b[3]);
  f16x8 o;
  o[0] = (_Float16)p0[0]; o[1] = (_Float16)p0[1];
  o[2] = (_Float16)p1[0]; o[3] = (_Float16)p1[1];
  o[4] = (_Float16)p2[0]; o[5] = (_Float16)p2[1];
  o[6] = (_Float16)p3[0]; o[7] = (_Float16)p3[1];
  return o;
}

__device__ __forceinline__ float tanh_fast(float v) {
  float a = fminf(fabsf(v), 18.f);
  float t = __expf(2.f * a);
  float r = (t - 1.f) * __builtin_amdgcn_rcpf(t + 1.f);
  return copysignf(r, v);
}

// Pack Wu/Wg/Wa/Wd -> wsB f16, PRE-SWIZZLED (R6 layout, verified):
// wsB[cb*65536 + row*512 + kt*64 + slot*8 + b], k = kt*64 + (slot^(row&7))*8 + b.
// strip: 0=Wu (K zero-padded for k>=256), 1=Wg, 2=Wa, 3=Wd.
__global__ __launch_bounds__(256) void pack_w(const float* __restrict__ Wu,
                                              const float* __restrict__ Wg,
                                              const float* __restrict__ Wa,
                                              const float* __restrict__ Wd,
                                              _Float16* __restrict__ wsB) {
  int t = blockIdx.x * 256 + threadIdx.x;  // 65536 total
  int slot = t & 7;
  int kt = (t >> 3) & 7;
  int row = (t >> 6) & 127;
  int cb = t >> 13;
  int strip = (row >> 4) & 3;
  int wn = row >> 6;
  int t16 = row & 15;
  int c = cb * 32 + wn * 16 + t16;
  int k0 = kt * 64 + (slot ^ (row & 7)) * 8;
  float v[8];
  if (strip == 0) {
    if (k0 < 256) {
      const float* p = Wu + (size_t)c * 256 + k0;
#pragma unroll
      for (int i = 0; i < 8; ++i) v[i] = p[i];
    } else {
#pragma unroll
      for (int i = 0; i < 8; ++i) v[i] = 0.f;
    }
  } else {
    const float* p = (strip == 1 ? Wg : (strip == 2 ? Wa : Wd)) + (size_t)c * 512 + k0;
#pragma unroll
    for (int i = 0; i < 8; ++i) v[i] = p[i];
  }
  f32x4 a = {v[0], v[1], v[2], v[3]};
  f32x4 b = {v[4], v[5], v[6], v[7]};
  *reinterpret_cast<f16x8*>(wsB + (size_t)cb * 65536 + row * 512 + kt * 64 + slot * 8) =
      cvt8(a, b);
}

// Pack A = [x | h] f32 -> f16, PRE-SWIZZLED + glds-ready:
// wsA[tid*8], tid = rb<<12 | kt<<9 | row6<<3 | slot, holding
//   xh[rb*64+row6][k], k_global: kt<4 -> x col (kt*64 + (slot^(row6&7))*8),
//   kt>=4 -> h col ((kt-4)*64 + (slot^(row6&7))*8).
// Main kernel copies slab (rb,kt) linearly (64 rows x 8 slots x 16 B = 8 KB).
__global__ __launch_bounds__(256) void pack_a(const float* __restrict__ x,
                                              const float* __restrict__ h,
                                              _Float16* __restrict__ wsA) {
  int tid = blockIdx.x * 256 + threadIdx.x;  // 1,048,576 total
  int slot = tid & 7;
  int row6 = (tid >> 3) & 63;
  int kt = (tid >> 9) & 7;
  int rb = tid >> 12;
  int rowg = rb * 64 + row6;
  int kin = (kt & 3) * 64 + (slot ^ (row6 & 7)) * 8;
  const float* src = (kt < 4 ? x : h) + (size_t)rowg * 256 + kin;
  f32x4 a = *reinterpret_cast<const f32x4*>(src);
  f32x4 b = *reinterpret_cast<const f32x4*>(src + 4);
  *reinterpret_cast<f16x8*>(wsA + (size_t)tid * 8) = cvt8(a, b);
}

// Fused GEMM + epilogue. Block: 64 rows x 128 packed cols, 4 waves (2M x 2N),
// BK=64. BOTH operands staged via global_load_lds from pre-swizzled f16 ws
// (6 glds per kt, zero staging VALU). Double-buffered LDS (48 KB), counted
// vmcnt(6) + raw s_barrier: next-tile loads stay in flight across barriers.
__global__ __launch_bounds__(256, 3) void rwa_main(
    const float* __restrict__ nt_, const float* __restrict__ dt_,
    const float* __restrict__ amax_, const float* __restrict__ bu,
    const float* __restrict__ bg, const _Float16* __restrict__ wsA,
    const _Float16* __restrict__ wsB, float* __restrict__ out) {
  __shared__ __align__(16) _Float16 ldsA[2][64 * 64];   // 2 x 8 KB
  __shared__ __align__(16) _Float16 ldsB[2][128 * 64];  // 2 x 16 KB

  const int tid = threadIdx.x;
  const int lane = tid & 63;
  const int l15 = lane & 15;
  const int lg = lane >> 4;
  const int wv = tid >> 6;
  const int wm = wv & 1;   // wave row-half (32 rows)
  const int wn = wv >> 1;  // wave packed-col half (64)

  // XCD swizzle: per XCD, cb fastest -> row panels + weights L2-hot.
  const int bid = blockIdx.x;
  const int xcd = bid & 7;
  const int q = bid >> 3;
  const int cb = q & 7;
  const int rowblk = xcd * 32 + (q >> 3);  // == rb in wsA
  const int row0 = rowblk * 64;

  // Staging sources.
  const _Float16* asrc0 = wsA + (size_t)rowblk * 32768 + (size_t)tid * 8;  // + kt*4096 + i*2048
  const _Float16* bsrc0 = wsB + (size_t)cb * 65536 + (tid >> 3) * 512 + (tid & 7) * 8;  // + kt*64 + i*16384

  f32x4 acc[2][4] = {};  // [mi][strip]

  auto stage = [&](int buf, int kt) {
    // A: 2 x glds (8 KB slab, linear). Dest base wave-uniform; HW adds lane*16.
#pragma unroll
    for (int i = 0; i < 2; ++i) {
      __builtin_amdgcn_global_load_lds(
          (const __attribute__((address_space(1))) uint32_t*)(asrc0 + (size_t)kt * 4096 + i * 2048),
          (__attribute__((address_space(3))) uint32_t*)(&ldsA[buf][0] + wv * 512 + i * 2048),
          16, 0, 0);
    }
    // B: 4 x glds (16 KB slab, linear).
#pragma unroll
    for (int i = 0; i < 4; ++i) {
      __builtin_amdgcn_global_load_lds(
          (const __attribute__((address_space(1))) uint32_t*)(bsrc0 + (size_t)kt * 64 + i * 16384),
          (__attribute__((address_space(3))) uint32_t*)(&ldsB[buf][0] + wv * 512 + i * 2048),
          16, 0, 0);
    }
  };

  // Prologue: stage tile 0 into buf 0.
  stage(0, 0);

#pragma unroll
  for (int kt = 0; kt < 8; ++kt) {
    const int buf = kt & 1;
    if (kt < 7) stage(buf ^ 1, kt + 1);  // 6 glds into other buffer

    // Barrier 1: own tile-kt loads done (6 newest = tile kt+1 stay in flight).
    if (kt < 7) {
      asm volatile("s_waitcnt vmcnt(6)" ::: "memory");
    } else {
      asm volatile("s_waitcnt vmcnt(0)" ::: "memory");
    }
    __builtin_amdgcn_s_barrier();
    __builtin_amdgcn_sched_barrier(0);

    // Compute tile kt.
    const bool doU = (kt < 4);  // Wu strip zero-padded beyond k=256
    const char* pA = reinterpret_cast<const char*>(&ldsA[buf][0]);
    const char* pB = reinterpret_cast<const char*>(&ldsB[buf][0]);
    const int rswz = (l15 & 7) << 4;
#pragma unroll
    for (int ks = 0; ks < 2; ++ks) {
      f16x8 af[2], bf[4];
#pragma unroll
      for (int mi = 0; mi < 2; ++mi) {
        const int row = wm * 32 + mi * 16 + l15;
        af[mi] = *reinterpret_cast<const f16x8*>(pA + row * 128 + ((ks * 64 + lg * 16) ^ rswz));
      }
#pragma unroll
      for (int s = 0; s < 4; ++s) {
        if (s == 0 && !doU) continue;
        const int pc = wn * 64 + s * 16 + l15;
        bf[s] = *reinterpret_cast<const f16x8*>(pB + pc * 128 + ((ks * 64 + lg * 16) ^ rswz));
      }
#pragma unroll
      for (int s = 0; s < 4; ++s) {
        if (s == 0 && !doU) continue;
#pragma unroll
        for (int mi = 0; mi < 2; ++mi)
          acc[mi][s] = __builtin_amdgcn_mfma_f32_16x16x32_f16(af[mi], bf[s], acc[mi][s], 0, 0, 0);
      }
    }

    // Barrier 2: all waves done reading buf before next stage overwrites it.
    if (kt < 7) {
      asm volatile("s_waitcnt lgkmcnt(0)" ::: "memory");
      __builtin_amdgcn_s_barrier();
      __builtin_amdgcn_sched_barrier(0);
    }
  }

  __builtin_amdgcn_sched_barrier(0);  // keep epilogue loads below the loop

  // Epilogue: lane owns (r,c); u,g,a,dec local.
  const int c = cb * 32 + wn * 16 + l15;
  const float buv = bu[c];
  const float bgv = bg[c];
#pragma unroll
  for (int mi = 0; mi < 2; ++mi) {
#pragma unroll
    for (int rg = 0; rg < 4; ++rg) {
      const int r = row0 + wm * 32 + mi * 16 + lg * 4 + rg;
      const int idx = r * 256 + c;
      const float u = acc[mi][0][rg] + buv;
      const float gt = acc[mi][1][rg] + bgv;
      const float a = acc[mi][2][rg];
      const float dr = acc[mi][3][rg];
      const float sig = __builtin_amdgcn_rcpf(1.f + __expf(-dr));
      const float z = u * tanh_fast(gt);
      const float am = amax_[idx];
      const float n_old = nt_[idx];
      const float d_old = dt_[idx];
      const float e_neg = __expf(-sig);
      const float a_new = fmaxf(am * e_neg, a);
      const float comm = __expf(am - a_new - sig);  // e_neg * exp(am - a_new)
      const float escal = __expf(a - a_new);
      const float n_new = n_old * comm + z * escal;
      const float d_new = d_old * comm + escal;
      const float h_new = tanh_fast(n_new * __builtin_amdgcn_rcpf(d_new));
      out[idx] = n_new;
      out[BC + idx] = d_new;
      out[2 * BC + idx] = h_new;
      out[3 * BC + idx] = a_new;
    }
  }
}

extern "C" void kernel_launch(void* const* d_in, const int* in_sizes, int n_in,
                              void* d_out, int out_size, void* d_ws, size_t ws_size,
                              hipStream_t stream) {
  const float* x_t    = (const float*)d_in[0];
  const float* n_t    = (const float*)d_in[1];
  const float* d_t    = (const float*)d_in[2];
  const float* h_t    = (const float*)d_in[3];
  const float* amax_t = (const float*)d_in[4];
  const float* Wu     = (const float*)d_in[5];
  const float* bu     = (const float*)d_in[6];
  const float* Wg     = (const float*)d_in[7];
  const float* bg     = (const float*)d_in[8];
  const float* Wa     = (const float*)d_in[9];
  const float* Wd     = (const float*)d_in[10];
  float* out = (float*)d_out;

  _Float16* wsB = (_Float16*)d_ws;                         // 1 MB
  _Float16* wsA = (_Float16*)((char*)d_ws + 1048576);      // 16 MB

  pack_w<<<256, 256, 0, stream>>>(Wu, Wg, Wa, Wd, wsB);
  pack_a<<<4096, 256, 0, stream>>>(x_t, h_t, wsA);
  rwa_main<<<2048, 256, 0, stream>>>(n_t, d_t, amax_t, bu, bg, wsA, wsB, out);
}

// Round 13
// 48.752 us; speedup vs baseline: 1.4836x; 1.0656x over previous
//
#include <hip/hip_runtime.h>
#include <stdint.h>

typedef _Float16 f16x8 __attribute__((ext_vector_type(8)));
typedef __fp16 fp16x2 __attribute__((ext_vector_type(2)));
typedef float f32x4 __attribute__((ext_vector_type(4)));

#define BC (16384 * 256)

__device__ __forceinline__ f16x8 cvt8(f32x4 a, f32x4 b) {
  fp16x2 p0 = __builtin_amdgcn_cvt_pkrtz(a[0], a[1]);
  fp16x2 p1 = __builtin_amdgcn_cvt_pkrtz(a[2], a[3]);
  fp16x2 p2 = __builtin_amdgcn_cvt_pkrtz(b[0], b[1]);
  fp16x2 p3 = __builtin_amdgcn_cvt_pkrtz(b[2], b[3]);
  f16x8 o;
  o[0] = (_Float16)p0[0]; o[1] = (_Float16)p0[1];
  o[2] = (_Float16)p1[0]; o[3] = (_Float16)p1[1];
  o[4] = (_Float16)p2[0]; o[5] = (_Float16)p2[1];
  o[6] = (_Float16)p3[0]; o[7] = (_Float16)p3[1];
  return o;
}

__device__ __forceinline__ float tanh_fast(float v) {
  float a = fminf(fabsf(v), 18.f);
  float t = __expf(2.f * a);
  float r = (t - 1.f) * __builtin_amdgcn_rcpf(t + 1.f);
  return copysignf(r, v);
}

// Pack Wu/Wg/Wa/Wd -> wsB f16, PRE-SWIZZLED (R6 layout, verified):
// wsB[cb*65536 + row*512 + kt*64 + slot*8 + b], k = kt*64 + (slot^(row&7))*8 + b.
// strip: 0=Wu (K zero-padded for k>=256), 1=Wg, 2=Wa, 3=Wd.
__global__ __launch_bounds__(256) void pack_w(const float* __restrict__ Wu,
                                              const float* __restrict__ Wg,
                                              const float* __restrict__ Wa,
                                              const float* __restrict__ Wd,
                                              _Float16* __restrict__ wsB) {
  int t = blockIdx.x * 256 + threadIdx.x;  // 65536 total
  int slot = t & 7;
  int kt = (t >> 3) & 7;
  int row = (t >> 6) & 127;
  int cb = t >> 13;
  int strip = (row >> 4) & 3;
  int wn = row >> 6;
  int t16 = row & 15;
  int c = cb * 32 + wn * 16 + t16;
  int k0 = kt * 64 + (slot ^ (row & 7)) * 8;
  float v[8];
  if (strip == 0) {
    if (k0 < 256) {
      const float* p = Wu + (size_t)c * 256 + k0;
#pragma unroll
      for (int i = 0; i < 8; ++i) v[i] = p[i];
    } else {
#pragma unroll
      for (int i = 0; i < 8; ++i) v[i] = 0.f;
    }
  } else {
    const float* p = (strip == 1 ? Wg : (strip == 2 ? Wa : Wd)) + (size_t)c * 512 + k0;
#pragma unroll
    for (int i = 0; i < 8; ++i) v[i] = p[i];
  }
  f32x4 a = {v[0], v[1], v[2], v[3]};
  f32x4 b = {v[4], v[5], v[6], v[7]};
  *reinterpret_cast<f16x8*>(wsB + (size_t)cb * 65536 + row * 512 + kt * 64 + slot * 8) =
      cvt8(a, b);
}

// Fused GEMM + epilogue, counted-vmcnt pipeline (R12 skeleton), A staged
// in-main (no pack_a). Block: 64 rows x 128 packed cols, 4 waves (2M x 2N),
// BK=64, double-buffered LDS (48 KB -> 3 blocks/CU).
// Per iter: issue A-gloads(kt+1) then B-glds(kt+1); vmcnt(8) retires B(kt)
// only (8 newest stay in flight across s_barrier); compute; cvt+ds_write A
// (compiler waits A-loads only); lgkmcnt(0)+barrier.
__global__ __launch_bounds__(256, 3) void rwa_main(
    const float* __restrict__ x, const float* __restrict__ nt_,
    const float* __restrict__ dt_, const float* __restrict__ h,
    const float* __restrict__ amax_, const float* __restrict__ bu,
    const float* __restrict__ bg, const _Float16* __restrict__ wsB,
    float* __restrict__ out) {
  __shared__ __align__(16) _Float16 ldsA[2][64 * 64];   // 2 x 8 KB
  __shared__ __align__(16) _Float16 ldsB[2][128 * 64];  // 2 x 16 KB

  const int tid = threadIdx.x;
  const int lane = tid & 63;
  const int l15 = lane & 15;
  const int lg = lane >> 4;
  const int wv = tid >> 6;
  const int wm = wv & 1;   // wave row-half (32 rows)
  const int wn = wv >> 1;  // wave packed-col half (64)

  // XCD swizzle: 8 cb-blocks of one rowblk land on the same XCD -> A panel
  // fetched once per XCD L2; weights L2-hot.
  const int bid = blockIdx.x;
  const int xcd = bid & 7;
  const int q = bid >> 3;
  const int cb = q & 7;
  const int rowblk = xcd * 32 + (q >> 3);
  const int row0 = rowblk * 64;

  // A staging coords: thread stages row ar (0..63), k-quarter aq (16 floats).
  const int ar = tid >> 2;
  const int aq = tid & 3;

  // B staging source (R6 layout).
  const _Float16* bsrc0 = wsB + (size_t)cb * 65536 + (tid >> 3) * 512 + (tid & 7) * 8;

  f32x4 acc[2][4] = {};  // [mi][strip]
  f32x4 av[4];           // in-flight A staging regs (next tile)

  auto issueA = [&](int kt) {
    const float* sp = (kt < 4 ? x : h) + (size_t)(row0 + ar) * 256 + (kt & 3) * 64 + aq * 16;
#pragma unroll
    for (int i = 0; i < 4; ++i) av[i] = *reinterpret_cast<const f32x4*>(sp + i * 4);
  };
  auto issueB = [&](int buf, int kt) {
#pragma unroll
    for (int i = 0; i < 4; ++i) {
      __builtin_amdgcn_global_load_lds(
          (const __attribute__((address_space(1))) uint32_t*)(bsrc0 + (size_t)kt * 64 + i * 16384),
          (__attribute__((address_space(3))) uint32_t*)(&ldsB[buf][0] + wv * 512 + i * 2048),
          16, 0, 0);
    }
  };
  auto writeA = [&](int buf) {
#pragma unroll
    for (int j = 0; j < 2; ++j) {
      f16x8 o = cvt8(av[2 * j], av[2 * j + 1]);
      const int slot = (aq * 2 + j) ^ (ar & 7);
      *reinterpret_cast<f16x8*>(reinterpret_cast<char*>(&ldsA[buf][0]) + ar * 128 + slot * 16) = o;
    }
  };

  // Prologue: tile 0. A(0) gloads -> cvt -> ds_write; B(0) glds stay pending.
  issueA(0);
  issueB(0, 0);
  writeA(0);  // compiler inserts vmcnt(4): A(0) retired, B(0) in flight

#pragma unroll
  for (int kt = 0; kt < 8; ++kt) {
    const int buf = kt & 1;
    // Top: issue next tile (A first, then B -> vmcnt ordering below).
    if (kt < 7) {
      issueA(kt + 1);
      issueB(buf ^ 1, kt + 1);
    }

    // B1: retire B(kt) (own contributions), keep 8 newest in flight.
    if (kt < 7) {
      asm volatile("s_waitcnt vmcnt(8) lgkmcnt(0)" ::: "memory");
    } else {
      asm volatile("s_waitcnt vmcnt(0) lgkmcnt(0)" ::: "memory");
    }
    __builtin_amdgcn_s_barrier();
    __builtin_amdgcn_sched_barrier(0);

    // Compute tile kt.
    const bool doU = (kt < 4);  // Wu strip zero-padded beyond k=256
    const char* pA = reinterpret_cast<const char*>(&ldsA[buf][0]);
    const char* pB = reinterpret_cast<const char*>(&ldsB[buf][0]);
    const int rswz = (l15 & 7) << 4;
#pragma unroll
    for (int ks = 0; ks < 2; ++ks) {
      f16x8 af[2], bf[4];
#pragma unroll
      for (int mi = 0; mi < 2; ++mi) {
        const int row = wm * 32 + mi * 16 + l15;
        af[mi] = *reinterpret_cast<const f16x8*>(pA + row * 128 + ((ks * 64 + lg * 16) ^ rswz));
      }
#pragma unroll
      for (int s = 0; s < 4; ++s) {
        if (s == 0 && !doU) continue;
        const int pc = wn * 64 + s * 16 + l15;
        bf[s] = *reinterpret_cast<const f16x8*>(pB + pc * 128 + ((ks * 64 + lg * 16) ^ rswz));
      }
#pragma unroll
      for (int s = 0; s < 4; ++s) {
        if (s == 0 && !doU) continue;
#pragma unroll
        for (int mi = 0; mi < 2; ++mi)
          acc[mi][s] = __builtin_amdgcn_mfma_f32_16x16x32_f16(af[mi], bf[s], acc[mi][s], 0, 0, 0);
      }
    }

    if (kt < 7) {
      writeA(buf ^ 1);  // compiler-inserted vmcnt retires A(kt+1) only
      // B2: ds_write visible to all waves before next compute reads it.
      asm volatile("s_waitcnt lgkmcnt(0)" ::: "memory");
      __builtin_amdgcn_s_barrier();
      __builtin_amdgcn_sched_barrier(0);
    }
  }

  __builtin_amdgcn_sched_barrier(0);  // keep epilogue loads below the loop

  // Epilogue: lane owns (r,c); u,g,a,dec local.
  const int c = cb * 32 + wn * 16 + l15;
  const float buv = bu[c];
  const float bgv = bg[c];
#pragma unroll
  for (int mi = 0; mi < 2; ++mi) {
#pragma unroll
    for (int rg = 0; rg < 4; ++rg) {
      const int r = row0 + wm * 32 + mi * 16 + lg * 4 + rg;
      const int idx = r * 256 + c;
      const float u = acc[mi][0][rg] + buv;
      const float gt = acc[mi][1][rg] + bgv;
      const float a = acc[mi][2][rg];
      const float dr = acc[mi][3][rg];
      const float sig = __builtin_amdgcn_rcpf(1.f + __expf(-dr));
      const float z = u * tanh_fast(gt);
      const float am = amax_[idx];
      const float n_old = nt_[idx];
      const float d_old = dt_[idx];
      const float e_neg = __expf(-sig);
      const float a_new = fmaxf(am * e_neg, a);
      const float comm = __expf(am - a_new - sig);  // e_neg * exp(am - a_new)
      const float escal = __expf(a - a_new);
      const float n_new = n_old * comm + z * escal;
      const float d_new = d_old * comm + escal;
      const float h_new = tanh_fast(n_new * __builtin_amdgcn_rcpf(d_new));
      out[idx] = n_new;
      out[BC + idx] = d_new;
      out[2 * BC + idx] = h_new;
      out[3 * BC + idx] = a_new;
    }
  }
}

extern "C" void kernel_launch(void* const* d_in, const int* in_sizes, int n_in,
                              void* d_out, int out_size, void* d_ws, size_t ws_size,
                              hipStream_t stream) {
  const float* x_t    = (const float*)d_in[0];
  const float* n_t    = (const float*)d_in[1];
  const float* d_t    = (const float*)d_in[2];
  const float* h_t    = (const float*)d_in[3];
  const float* amax_t = (const float*)d_in[4];
  const float* Wu     = (const float*)d_in[5];
  const float* bu     = (const float*)d_in[6];
  const float* Wg     = (const float*)d_in[7];
  const float* bg     = (const float*)d_in[8];
  const float* Wa     = (const float*)d_in[9];
  const float* Wd     = (const float*)d_in[10];
  float* out = (float*)d_out;

  _Float16* wsB = (_Float16*)d_ws;  // 1 MB pre-swizzled packed weights

  pack_w<<<256, 256, 0, stream>>>(Wu, Wg, Wa, Wd, wsB);
  rwa_main<<<2048, 256, 0, stream>>>(x_t, n_t, d_t, h_t, amax_t, bu, bg, wsB, out);
}

// Round 14
// 46.133 us; speedup vs baseline: 1.5678x; 1.0568x over previous
//
#include <hip/hip_runtime.h>
#include <stdint.h>

typedef _Float16 f16x8 __attribute__((ext_vector_type(8)));
typedef __fp16 fp16x2 __attribute__((ext_vector_type(2)));
typedef float f32x4 __attribute__((ext_vector_type(4)));

#define BC (16384 * 256)

__device__ __forceinline__ f16x8 cvt8(f32x4 a, f32x4 b) {
  fp16x2 p0 = __builtin_amdgcn_cvt_pkrtz(a[0], a[1]);
  fp16x2 p1 = __builtin_amdgcn_cvt_pkrtz(a[2], a[3]);
  fp16x2 p2 = __builtin_amdgcn_cvt_pkrtz(b[0], b[1]);
  fp16x2 p3 = __builtin_amdgcn_cvt_pkrtz(b[2], b[3]);
  f16x8 o;
  o[0] = (_Float16)p0[0]; o[1] = (_Float16)p0[1];
  o[2] = (_Float16)p1[0]; o[3] = (_Float16)p1[1];
  o[4] = (_Float16)p2[0]; o[5] = (_Float16)p2[1];
  o[6] = (_Float16)p3[0]; o[7] = (_Float16)p3[1];
  return o;
}

__device__ __forceinline__ float tanh_fast(float v) {
  float a = fminf(fabsf(v), 18.f);
  float t = __expf(2.f * a);
  float r = (t - 1.f) * __builtin_amdgcn_rcpf(t + 1.f);
  return copysignf(r, v);
}

// Pack Wu/Wg/Wa/Wd -> wsB f16, kt-outermost, BK=32 LDS swizzle baked in
// (R8 layout, correctness-verified):
// elem = (((kt*8 + cb)*128 + row)*4 + slot)*8 + b, holding W_strip[c][k] with
//   row = wn*64 + strip*16 + t16, c = cb*32 + wn*16 + t16,
//   k = kt*32 + (slot ^ ((row>>1)&3))*8 + b.
// Per (kt,cb) slab: 8 KB, copied linearly by 2 glds rounds of 4 KB.
// strip 0 = Wu (k >= 256 zero-padded).
__global__ __launch_bounds__(256) void pack_w(const float* __restrict__ Wu,
                                              const float* __restrict__ Wg,
                                              const float* __restrict__ Wa,
                                              const float* __restrict__ Wd,
                                              _Float16* __restrict__ wsB) {
  int tid = blockIdx.x * 256 + threadIdx.x;  // 65536 total
  int slot = tid & 3;
  int row = (tid >> 2) & 127;
  int cb = (tid >> 9) & 7;
  int kt = tid >> 12;  // 0..15
  int strip = (row >> 4) & 3;
  int wn = row >> 6;
  int t16 = row & 15;
  int c = cb * 32 + wn * 16 + t16;
  int k0 = kt * 32 + (slot ^ ((row >> 1) & 3)) * 8;
  float v[8];
  if (strip == 0) {
    if (k0 < 256) {
      const float* p = Wu + (size_t)c * 256 + k0;
#pragma unroll
      for (int i = 0; i < 8; ++i) v[i] = p[i];
    } else {
#pragma unroll
      for (int i = 0; i < 8; ++i) v[i] = 0.f;
    }
  } else {
    const float* p = (strip == 1 ? Wg : (strip == 2 ? Wa : Wd)) + (size_t)c * 512 + k0;
#pragma unroll
    for (int i = 0; i < 8; ++i) v[i] = p[i];
  }
  f32x4 a = {v[0], v[1], v[2], v[3]};
  f32x4 b = {v[4], v[5], v[6], v[7]};
  *reinterpret_cast<f16x8*>(wsB + (size_t)tid * 8) = cvt8(a, b);
}

// Fused GEMM + epilogue: R13's counted-vmcnt pipeline at BK=32 for occupancy.
// Block: 64 rows x 128 packed cols, 4 waves (2M x 2N), double-buffered LDS
// (2x4 + 2x8 = 24 KB -> 6 blocks/CU, 24 waves/CU). Per iter (16 total):
// issue A-gloads(kt+1) + B-glds(kt+1) [4 VMEM]; vmcnt(4) retires B(kt) only;
// barrier; one MFMA pass (k=32); cvt+ds_write A(kt+1) (implicit vmcnt(2));
// lgkmcnt(0); barrier.
__global__ __launch_bounds__(256, 6) void rwa_main(
    const float* __restrict__ x, const float* __restrict__ nt_,
    const float* __restrict__ dt_, const float* __restrict__ h,
    const float* __restrict__ amax_, const float* __restrict__ bu,
    const float* __restrict__ bg, const _Float16* __restrict__ wsB,
    float* __restrict__ out) {
  __shared__ __align__(16) _Float16 ldsA[2][64 * 32];   // 2 x 4 KB
  __shared__ __align__(16) _Float16 ldsB[2][128 * 32];  // 2 x 8 KB

  const int tid = threadIdx.x;
  const int lane = tid & 63;
  const int l15 = lane & 15;
  const int lg = lane >> 4;
  const int wv = tid >> 6;
  const int wm = wv & 1;   // wave row-half (32 rows)
  const int wn = wv >> 1;  // wave packed-col half (64)

  // XCD swizzle: 8 cb-blocks of one rowblk share an XCD -> A panel + weights L2-hot.
  const int bid = blockIdx.x;
  const int xcd = bid & 7;
  const int q = bid >> 3;
  const int cb = q & 7;
  const int rowblk = xcd * 32 + (q >> 3);
  const int row0 = rowblk * 64;

  // A staging: thread stages row ar (0..63), 8-float chunk aq (0..3).
  const int ar = tid >> 2;
  const int aq = tid & 3;
  const int awoff = ar * 64 + ((aq ^ ((ar >> 1) & 3)) << 4);  // swizzled byte off

  // B staging source (R8 layout): per (kt,cb) slab 8 KB; thread t copies 16 B.
  const _Float16* bsrc0 = wsB + (size_t)cb * 4096 + (size_t)tid * 8;

  f32x4 acc[2][4] = {};  // [mi][strip]
  f32x4 a0, a1;          // in-flight A staging regs (next tile)

  auto issueA = [&](int kt) {
    const float* sp = (kt < 8 ? x : h) + (size_t)(row0 + ar) * 256 + (kt & 7) * 32 + aq * 8;
    a0 = *reinterpret_cast<const f32x4*>(sp);
    a1 = *reinterpret_cast<const f32x4*>(sp + 4);
  };
  auto issueB = [&](int buf, int kt) {
#pragma unroll
    for (int i = 0; i < 2; ++i) {
      __builtin_amdgcn_global_load_lds(
          (const __attribute__((address_space(1))) uint32_t*)(bsrc0 + (size_t)kt * 32768 + i * 2048),
          (__attribute__((address_space(3))) uint32_t*)(&ldsB[buf][0] + wv * 512 + i * 2048),
          16, 0, 0);
    }
  };
  auto writeA = [&](int buf) {
    *reinterpret_cast<f16x8*>(reinterpret_cast<char*>(&ldsA[buf][0]) + awoff) = cvt8(a0, a1);
  };

  // Prologue: tile 0 into buf 0. B(0) glds stay pending until first B1.
  issueA(0);
  issueB(0, 0);
  writeA(0);  // compiler inserts vmcnt wait for a0/a1 only

#pragma unroll
  for (int kt = 0; kt < 16; ++kt) {
    const int buf = kt & 1;
    // Top: issue next tile (A first, then B -> vmcnt ordering below).
    if (kt < 15) {
      issueA(kt + 1);
      issueB(buf ^ 1, kt + 1);
    }

    // B1: retire B(kt); tile kt+1's 4 VMEM ops stay in flight across barrier.
    if (kt < 15) {
      asm volatile("s_waitcnt vmcnt(4) lgkmcnt(0)" ::: "memory");
    } else {
      asm volatile("s_waitcnt vmcnt(0) lgkmcnt(0)" ::: "memory");
    }
    __builtin_amdgcn_s_barrier();
    __builtin_amdgcn_sched_barrier(0);

    // Compute tile kt: one MFMA pass (k=32 = full BK).
    const bool doU = (kt < 8);  // Wu strip zero-padded beyond k=256
    const char* pA = reinterpret_cast<const char*>(&ldsA[buf][0]);
    const char* pB = reinterpret_cast<const char*>(&ldsB[buf][0]);
    {
      f16x8 af[2], bf[4];
#pragma unroll
      for (int mi = 0; mi < 2; ++mi) {
        const int row = wm * 32 + mi * 16 + l15;
        af[mi] = *reinterpret_cast<const f16x8*>(pA + row * 64 + ((lg ^ ((row >> 1) & 3)) << 4));
      }
#pragma unroll
      for (int s = 0; s < 4; ++s) {
        if (s == 0 && !doU) continue;
        const int pc = wn * 64 + s * 16 + l15;
        bf[s] = *reinterpret_cast<const f16x8*>(pB + pc * 64 + ((lg ^ ((pc >> 1) & 3)) << 4));
      }
#pragma unroll
      for (int s = 0; s < 4; ++s) {
        if (s == 0 && !doU) continue;
#pragma unroll
        for (int mi = 0; mi < 2; ++mi)
          acc[mi][s] = __builtin_amdgcn_mfma_f32_16x16x32_f16(af[mi], bf[s], acc[mi][s], 0, 0, 0);
      }
    }

    if (kt < 15) {
      writeA(buf ^ 1);  // implicit vmcnt(2): waits A(kt+1) gloads only
      asm volatile("s_waitcnt lgkmcnt(0)" ::: "memory");
      __builtin_amdgcn_s_barrier();
      __builtin_amdgcn_sched_barrier(0);
    }
  }

  __builtin_amdgcn_sched_barrier(0);  // keep epilogue loads below the loop

  // Epilogue: lane owns (r,c); u,g,a,dec local.
  const int c = cb * 32 + wn * 16 + l15;
  const float buv = bu[c];
  const float bgv = bg[c];
#pragma unroll
  for (int mi = 0; mi < 2; ++mi) {
#pragma unroll
    for (int rg = 0; rg < 4; ++rg) {
      const int r = row0 + wm * 32 + mi * 16 + lg * 4 + rg;
      const int idx = r * 256 + c;
      const float u = acc[mi][0][rg] + buv;
      const float gt = acc[mi][1][rg] + bgv;
      const float a = acc[mi][2][rg];
      const float dr = acc[mi][3][rg];
      const float sig = __builtin_amdgcn_rcpf(1.f + __expf(-dr));
      const float z = u * tanh_fast(gt);
      const float am = amax_[idx];
      const float n_old = nt_[idx];
      const float d_old = dt_[idx];
      const float e_neg = __expf(-sig);
      const float a_new = fmaxf(am * e_neg, a);
      const float comm = __expf(am - a_new - sig);  // e_neg * exp(am - a_new)
      const float escal = __expf(a - a_new);
      const float n_new = n_old * comm + z * escal;
      const float d_new = d_old * comm + escal;
      const float h_new = tanh_fast(n_new * __builtin_amdgcn_rcpf(d_new));
      out[idx] = n_new;
      out[BC + idx] = d_new;
      out[2 * BC + idx] = h_new;
      out[3 * BC + idx] = a_new;
    }
  }
}

extern "C" void kernel_launch(void* const* d_in, const int* in_sizes, int n_in,
                              void* d_out, int out_size, void* d_ws, size_t ws_size,
                              hipStream_t stream) {
  const float* x_t    = (const float*)d_in[0];
  const float* n_t    = (const float*)d_in[1];
  const float* d_t    = (const float*)d_in[2];
  const float* h_t    = (const float*)d_in[3];
  const float* amax_t = (const float*)d_in[4];
  const float* Wu     = (const float*)d_in[5];
  const float* bu     = (const float*)d_in[6];
  const float* Wg     = (const float*)d_in[7];
  const float* bg     = (const float*)d_in[8];
  const float* Wa     = (const float*)d_in[9];
  const float* Wd     = (const float*)d_in[10];
  float* out = (float*)d_out;

  _Float16* wsB = (_Float16*)d_ws;  // 1 MB packed weights (kt-outermost, BK=32)

  pack_w<<<256, 256, 0, stream>>>(Wu, Wg, Wa, Wd, wsB);
  rwa_main<<<2048, 256, 0, stream>>>(x_t, n_t, d_t, h_t, amax_t, bu, bg, wsB, out);
}